// Round 1
// baseline (476.724 us; speedup 1.0000x reference)
//
#include <hip/hip_runtime.h>

#define KH 5
#define KW 5
#define CIN 16
#define NF 32
#define H 224
#define W 224
#define HO 220
#define WO 220
#define RPB 4              // output rows per block (one per wave)
#define XROWS (RPB + KH - 1)   // 8 input rows staged
#define WPAD 32            // taps padded 25 -> 32 floats (128 B) for s_load_dwordx16

// ---- pre-kernel: transpose weights [tap][c][f] -> Wt[c][f][tap(pad 32)] ----
__global__ void transpose_weights(const float* __restrict__ Kw,
                                  float* __restrict__ Wt) {
    int idx = blockIdx.x * 256 + threadIdx.x;     // over KH*KW*CIN*NF = 12800
    if (idx < KH * KW * CIN * NF) {
        const int tap = idx / (CIN * NF);
        const int rem = idx - tap * (CIN * NF);
        const int c   = rem >> 5;                 // / NF
        const int f   = rem & 31;                 // % NF
        Wt[((size_t)(c * NF) + f) * WPAD + tap] = Kw[idx];
    }
}

// ---- main kernel: one block per (c, ho-tile of 4, b); one WAVE per output row ----
// Each wave holds a 5-row x 8-float window in 40 VGPRs (vs 64 before) and a
// 4-float accumulator (vs 16), iterating all 32 filters. Lower VGPR footprint
// -> ~7 waves/SIMD occupancy (vs ~4) to hide gather/s_load/store stalls.
// Math exact in fp32 (x < 256, |k| <= 8, sums < 2^24).
__global__ __launch_bounds__(256, 4) void conv2d_main(
    const float* __restrict__ X,    // [B, H, W, CIN]
    const float* __restrict__ Wt,   // [CIN, NF, WPAD]
    float* __restrict__ O)          // [B, HO, CIN, NF, WO]
{
    __shared__ float xs[XROWS * W];   // 7168 B

    const int c   = blockIdx.x;
    const int ho0 = blockIdx.y * RPB;
    const int b   = blockIdx.z;
    const int t   = threadIdx.x;

    // stage input rows ho0..ho0+7 of channel c (strided gather by CIN floats)
    const float* xbase = X + ((size_t)(b * H + ho0) * W) * CIN + c;
    for (int idx = t; idx < XROWS * W; idx += 256)
        xs[idx] = xbase[(size_t)idx * CIN];
    __syncthreads();

    const int wave = t >> 6;         // output row = ho0 + wave
    const int lane = t & 63;
    const int wo0  = lane * 4;
    if (lane >= 55) return;          // 55*4 = 220 = WO; no barrier after this

    // x window: 5 rows x 8 floats per lane (taps j+q for 4 wo) -> 40 VGPRs
    float xw[KH][8];
#pragma unroll
    for (int i = 0; i < KH; ++i) {
        const float4 xa = *(const float4*)&xs[(wave + i) * W + wo0];
        const float4 xb = *(const float4*)&xs[(wave + i) * W + wo0 + 4];
        xw[i][0] = xa.x; xw[i][1] = xa.y; xw[i][2] = xa.z; xw[i][3] = xa.w;
        xw[i][4] = xb.x; xw[i][5] = xb.y; xw[i][6] = xb.z; xw[i][7] = xb.w;
    }

    // this wave's output row base; per-filter stride is WO floats
    const size_t obase =
        (((size_t)(b * HO + ho0 + wave) * CIN + c) * NF) * WO + wo0;
    const float* wc = Wt + (size_t)(c * NF) * WPAD;

    // unroll 2: overlap next filter's scalar weight loads with current FMAs;
    // 8 independent FMA chains in flight (4 acc x 2 filters)
#pragma unroll 2
    for (int f = 0; f < NF; ++f) {
        const float* wp = wc + (size_t)f * WPAD;   // 128-B aligned, contiguous
        float wk[KH * KW];
#pragma unroll
        for (int tap = 0; tap < KH * KW; ++tap)
            wk[tap] = wp[tap];                     // uniform -> s_load_dwordx16 x2

        float a0 = 0.0f, a1 = 0.0f, a2 = 0.0f, a3 = 0.0f;
#pragma unroll
        for (int i = 0; i < KH; ++i)
#pragma unroll
            for (int j = 0; j < KW; ++j) {
                const float w = wk[i * KW + j];
                a0 += xw[i][j + 0] * w;
                a1 += xw[i][j + 1] * w;
                a2 += xw[i][j + 2] * w;
                a3 += xw[i][j + 3] * w;
            }

        *(float4*)&O[obase + (size_t)f * WO] = make_float4(a0, a1, a2, a3);
    }
}

extern "C" void kernel_launch(void* const* d_in, const int* in_sizes, int n_in,
                              void* d_out, int out_size, void* d_ws, size_t ws_size,
                              hipStream_t stream) {
    const float* X  = (const float*)d_in[0];
    const float* Kw = (const float*)d_in[1];
    float* O        = (float*)d_out;
    float* Wt       = (float*)d_ws;   // 16*32*32*4 = 64 KB scratch

    transpose_weights<<<dim3(50), 256, 0, stream>>>(Kw, Wt);
    dim3 grid(CIN, HO / RPB, 4);      // (c, ho-tile, b) = 16 x 55 x 4
    conv2d_main<<<grid, 256, 0, stream>>>(X, Wt, O);
}

// Round 2
// 449.703 us; speedup vs baseline: 1.0601x; 1.0601x over previous
//
#include <hip/hip_runtime.h>

#define KH 5
#define KW 5
#define CIN 16
#define NF 32
#define H 224
#define W 224
#define HO 220
#define WO 220
#define RPB 4              // output rows per block
#define XROWS (RPB + KH - 1)   // 8 input rows staged
#define WPAD 32            // taps padded 25 -> 32 floats (128 B) for s_load_dwordx16
#define NTILE (HO / RPB)   // 55 ho-tiles
#define NBLK (CIN * NTILE * 4)  // 3520 blocks; 3520 % 8 == 0 -> bijective XCD swizzle
#define NXCD 8
#define CPX (NBLK / NXCD)  // 440 blocks per XCD chunk

// ---- pre-kernel: transpose weights [tap][c][f] -> Wt[c][f][tap(pad 32)] ----
__global__ void transpose_weights(const float* __restrict__ Kw,
                                  float* __restrict__ Wt) {
    int idx = blockIdx.x * 256 + threadIdx.x;     // over KH*KW*CIN*NF = 12800
    if (idx < KH * KW * CIN * NF) {
        const int tap = idx / (CIN * NF);
        const int rem = idx - tap * (CIN * NF);
        const int c   = rem >> 5;                 // / NF
        const int f   = rem & 31;                 // % NF
        Wt[((size_t)(c * NF) + f) * WPAD + tap] = Kw[idx];
    }
}

// ---- main kernel: one block per (c, ho-tile of 4, b); wave -> filter octet ----
// Round-0 structure (best measured): each wave computes 8 filters x 4 rows,
// 400 FMAs per filter in 16 independent chains; weights via 2 uniform
// s_load_dwordx16 from a 128-B-aligned line.
// NEW: XCD-chunked blockIdx swizzle. The 16 c-blocks sharing the same 8 input
// rows (every 128-B line of X holds all 16 channels) land on ONE XCD's L2
// instead of being round-robined across all 8 -> input HBM fetch ~8x lower,
// and each XCD writes one contiguous output region (store page locality).
// Math exact in fp32 (x < 256, |k| <= 8, sums < 2^24).
__global__ __launch_bounds__(256) void conv2d_main(
    const float* __restrict__ X,    // [B, H, W, CIN]
    const float* __restrict__ Wt,   // [CIN, NF, WPAD]
    float* __restrict__ O)          // [B, HO, CIN, NF, WO]
{
    __shared__ float xs[XROWS * W];   // 7168 B

    // bijective XCD swizzle: hw blocks i, i+8, i+16.. (dispatched to XCD i)
    // execute the contiguous logical chunk [i*CPX, (i+1)*CPX)
    const int bid = blockIdx.x;
    const int l   = (bid & 7) * CPX + (bid >> 3);
    const int c   = l & 15;            // logical order: c fastest, then hoT, b
    const int rest = l >> 4;
    const int hoT = rest % NTILE;
    const int b   = rest / NTILE;
    const int ho0 = hoT * RPB;
    const int t   = threadIdx.x;

    // stage input rows ho0..ho0+7 of channel c (strided gather by CIN floats)
    const uint32_t xoff = ((uint32_t)(b * H + ho0) * W) * CIN + c;
    for (int idx = t; idx < XROWS * W; idx += 256)
        xs[idx] = X[xoff + (uint32_t)idx * CIN];
    __syncthreads();

    const int wave = t >> 6;
    const int lane = t & 63;
    const int wo0  = lane * 4;
    if (lane >= 55) return;          // 55*4 = 220 = WO; no barrier after this

    // x window: 8 rows x 8 floats per lane (taps j+col for 4 wo)
    float xr[XROWS][8];
#pragma unroll
    for (int r = 0; r < XROWS; ++r) {
        const float4 xa = *(const float4*)&xs[r * W + wo0];
        const float4 xb = *(const float4*)&xs[r * W + wo0 + 4];
        xr[r][0] = xa.x; xr[r][1] = xa.y; xr[r][2] = xa.z; xr[r][3] = xa.w;
        xr[r][4] = xb.x; xr[r][5] = xb.y; xr[r][6] = xb.z; xr[r][7] = xb.w;
    }

    // per-output-row store bases (uint32: total output floats < 2^31)
    uint32_t obase[RPB];
#pragma unroll
    for (int r = 0; r < RPB; ++r)
        obase[r] = (((uint32_t)(b * HO + ho0 + r) * CIN + c) * NF) * WO + wo0;

    const float* wc = Wt + (size_t)(c * NF) * WPAD;

#pragma unroll 1
    for (int fi = 0; fi < 8; ++fi) {
        const int f = __builtin_amdgcn_readfirstlane(wave * 8 + fi);
        const float* wp = wc + (size_t)f * WPAD;   // 128-B aligned, contiguous
        float wk[KH * KW];
#pragma unroll
        for (int tap = 0; tap < KH * KW; ++tap)
            wk[tap] = wp[tap];                     // uniform -> s_load_dwordx16 x2

        float acc[RPB][4];
#pragma unroll
        for (int r = 0; r < RPB; ++r)
#pragma unroll
            for (int q = 0; q < 4; ++q) acc[r][q] = 0.0f;

#pragma unroll
        for (int i = 0; i < KH; ++i)
#pragma unroll
            for (int j = 0; j < KW; ++j) {
                const float w = wk[i * KW + j];
#pragma unroll
                for (int r = 0; r < RPB; ++r) {
                    acc[r][0] += xr[r + i][j + 0] * w;
                    acc[r][1] += xr[r + i][j + 1] * w;
                    acc[r][2] += xr[r + i][j + 2] * w;
                    acc[r][3] += xr[r + i][j + 3] * w;
                }
            }

#pragma unroll
        for (int r = 0; r < RPB; ++r)
            *(float4*)&O[obase[r] + (uint32_t)f * WO] =
                make_float4(acc[r][0], acc[r][1], acc[r][2], acc[r][3]);
    }
}

extern "C" void kernel_launch(void* const* d_in, const int* in_sizes, int n_in,
                              void* d_out, int out_size, void* d_ws, size_t ws_size,
                              hipStream_t stream) {
    const float* X  = (const float*)d_in[0];
    const float* Kw = (const float*)d_in[1];
    float* O        = (float*)d_out;
    float* Wt       = (float*)d_ws;   // 16*32*32*4 = 64 KB scratch

    transpose_weights<<<dim3(50), 256, 0, stream>>>(Kw, Wt);
    conv2d_main<<<dim3(NBLK), 256, 0, stream>>>(X, Wt, O);
}

// Round 4
// 408.100 us; speedup vs baseline: 1.1682x; 1.1019x over previous
//
#include <hip/hip_runtime.h>

#define KH 5
#define KW 5
#define CIN 16
#define NF 32
#define H 224
#define W 224
#define HO 220
#define WO 220
#define RPB 4              // output rows per block
#define XROWS (RPB + KH - 1)   // 8 input rows staged
#define WPAD 32            // taps padded 25 -> 32 floats (128 B) for s_load_dwordx16
#define NTILE (HO / RPB)   // 55 ho-tiles
#define NBLK (CIN * NTILE * 4)  // 3520 blocks; 3520 % 8 == 0 -> bijective XCD swizzle
#define NXCD 8
#define CPX (NBLK / NXCD)  // 440 blocks per XCD chunk

// ---- pre-kernel: transpose weights [tap][c][f] -> Wt[c][f][tap(pad 32)] ----
__global__ void transpose_weights(const float* __restrict__ Kw,
                                  float* __restrict__ Wt) {
    int idx = blockIdx.x * 256 + threadIdx.x;     // over KH*KW*CIN*NF = 12800
    if (idx < KH * KW * CIN * NF) {
        const int tap = idx / (CIN * NF);
        const int rem = idx - tap * (CIN * NF);
        const int c   = rem >> 5;                 // / NF
        const int f   = rem & 31;                 // % NF
        Wt[((size_t)(c * NF) + f) * WPAD + tap] = Kw[idx];
    }
}

// compute one filter's 4x4 accumulators from the register window and store
__device__ __forceinline__ void compute_store(
    const float (&xr)[XROWS][8], const float (&wk)[KH * KW],
    const uint32_t (&obase)[RPB], int f, float* __restrict__ O)
{
    float acc[RPB][4];
#pragma unroll
    for (int r = 0; r < RPB; ++r)
#pragma unroll
        for (int q = 0; q < 4; ++q) acc[r][q] = 0.0f;

#pragma unroll
    for (int i = 0; i < KH; ++i)
#pragma unroll
        for (int j = 0; j < KW; ++j) {
            const float w = wk[i * KW + j];
#pragma unroll
            for (int r = 0; r < RPB; ++r) {
                acc[r][0] += xr[r + i][j + 0] * w;
                acc[r][1] += xr[r + i][j + 1] * w;
                acc[r][2] += xr[r + i][j + 2] * w;
                acc[r][3] += xr[r + i][j + 3] * w;
            }
        }

#pragma unroll
    for (int r = 0; r < RPB; ++r)
        *(float4*)&O[obase[r] + (uint32_t)f * WO] =
            make_float4(acc[r][0], acc[r][1], acc[r][2], acc[r][3]);
}

// ---- main kernel: one block per (c, ho-tile of 4, b); wave -> filter octet ----
// Round-0 structure (best measured) + 2-deep software pipeline on the uniform
// weight s_loads: each ping-pong buffer's loads are issued one full 400-FMA
// block (~800 cyc) before first use, hiding K$/L2/L3 miss latency that was
// previously exposed 8x per wave behind an lgkmcnt(0) each iteration.
// Math exact in fp32 (x < 256, |k| <= 8, sums < 2^24).
__global__ __launch_bounds__(256) void conv2d_main(
    const float* __restrict__ X,    // [B, H, W, CIN]
    const float* __restrict__ Wt,   // [CIN, NF, WPAD]
    float* __restrict__ O)          // [B, HO, CIN, NF, WO]
{
    __shared__ float xs[XROWS * W];   // 7168 B

    // bijective XCD swizzle: hw blocks i, i+8, .. execute logical chunk i
    const int bid = blockIdx.x;
    const int l   = (bid & 7) * CPX + (bid >> 3);
    const int c   = l & 15;            // logical order: c fastest, then hoT, b
    const int rest = l >> 4;
    const int hoT = rest % NTILE;
    const int b   = rest / NTILE;
    const int ho0 = hoT * RPB;
    const int t   = threadIdx.x;

    // stage input rows ho0..ho0+7 of channel c (strided gather by CIN floats)
    // 1792 = 7*256 exactly: full unroll -> all 7 loads issue back-to-back
    const uint32_t xoff = ((uint32_t)(b * H + ho0) * W) * CIN + c;
#pragma unroll
    for (int k = 0; k < XROWS * W / 256; ++k) {
        const int idx = t + k * 256;
        xs[idx] = X[xoff + (uint32_t)idx * CIN];
    }
    __syncthreads();

    const int wave = t >> 6;
    const int lane = t & 63;
    const int wo0  = lane * 4;
    if (lane >= 55) return;          // 55*4 = 220 = WO; no barrier after this

    // x window: 8 rows x 8 floats per lane (taps j+col for 4 wo)
    float xr[XROWS][8];
#pragma unroll
    for (int r = 0; r < XROWS; ++r) {
        const float4 xa = *(const float4*)&xs[r * W + wo0];
        const float4 xb = *(const float4*)&xs[r * W + wo0 + 4];
        xr[r][0] = xa.x; xr[r][1] = xa.y; xr[r][2] = xa.z; xr[r][3] = xa.w;
        xr[r][4] = xb.x; xr[r][5] = xb.y; xr[r][6] = xb.z; xr[r][7] = xb.w;
    }

    // per-output-row store bases (uint32: total output floats < 2^31)
    uint32_t obase[RPB];
#pragma unroll
    for (int r = 0; r < RPB; ++r)
        obase[r] = (((uint32_t)(b * HO + ho0 + r) * CIN + c) * NF) * WO + wo0;

    const float* wc = Wt + (size_t)(c * NF) * WPAD;
    const int f0 = __builtin_amdgcn_readfirstlane(wave * 8);

    // 2-deep ping-pong weight pipeline (uniform addresses -> SGPR s_loads)
    float wkA[KH * KW], wkB[KH * KW];
    {
        const float* wp = wc + (size_t)f0 * WPAD;
#pragma unroll
        for (int tap = 0; tap < KH * KW; ++tap) wkA[tap] = wp[tap];
    }

#pragma unroll 1
    for (int fi = 0; fi < 8; fi += 2) {
        // prefetch filter fi+1 into B before consuming A
        {
            const float* wp = wc + (size_t)(f0 + fi + 1) * WPAD;
#pragma unroll
            for (int tap = 0; tap < KH * KW; ++tap) wkB[tap] = wp[tap];
        }
        compute_store(xr, wkA, obase, f0 + fi, O);

        // prefetch filter fi+2 into A ( &7 wraps last iter in-bounds, unused )
        {
            const float* wp = wc + (size_t)(f0 + ((fi + 2) & 7)) * WPAD;
#pragma unroll
            for (int tap = 0; tap < KH * KW; ++tap) wkA[tap] = wp[tap];
        }
        compute_store(xr, wkB, obase, f0 + fi + 1, O);
    }
}

extern "C" void kernel_launch(void* const* d_in, const int* in_sizes, int n_in,
                              void* d_out, int out_size, void* d_ws, size_t ws_size,
                              hipStream_t stream) {
    const float* X  = (const float*)d_in[0];
    const float* Kw = (const float*)d_in[1];
    float* O        = (float*)d_out;
    float* Wt       = (float*)d_ws;   // 16*32*32*4 = 64 KB scratch

    transpose_weights<<<dim3(50), 256, 0, stream>>>(Kw, Wt);
    conv2d_main<<<dim3(NBLK), 256, 0, stream>>>(X, Wt, O);
}